// Round 2
// 216.022 us; speedup vs baseline: 1.0053x; 1.0053x over previous
//
#include <hip/hip_runtime.h>
#include <math.h>

// Problem constants: x is [B=16, H=64, W=64, G*C=512], G=8, C=64.
#define BATCH   16
#define HW      4096          // H*W
#define NPAIR   36            // upper-triangular 8x8 pairs
#define F4_PER_POS   128      // 512 floats / 4
#define F4_PER_GROUP 16       // 64 floats / 4
#define SLOTS_PER_B  65536    // HW * 16 float4-slots per batch
#define XB_F4        524288   // HW * 128 float4 per batch
#define BLOCKS_PER_BATCH 64
#define NBLOCKS (BATCH * BLOCKS_PER_BATCH)   // 1024 blocks

typedef float f4v __attribute__((ext_vector_type(4)));

// ---------------------------------------------------------------------------
// Kernel 1: per-block 36-entry Gram partials -> P[block*36 + p].
// No memset needed (each block owns its slot), no atomics.
// grid = 1024, block = 256; 4 float4-slots per thread.
// ---------------------------------------------------------------------------
__global__ __launch_bounds__(256) void gram_partial_kernel(
    const float* __restrict__ xf, float* __restrict__ P) {
    const float4* x = (const float4*)xf;
    const int tid = threadIdx.x;
    const int b   = blockIdx.x >> 6;
    const int blk = blockIdx.x & 63;
    const float4* xb = x + (long)b * XB_F4;

    float acc[NPAIR];
#pragma unroll
    for (int p = 0; p < NPAIR; ++p) acc[p] = 0.f;

    int slot = blk * 256 + tid;          // 4 slots/thread, stride 16384
#pragma unroll
    for (int it = 0; it < 4; ++it, slot += BLOCKS_PER_BATCH * 256) {
        const int pos = slot >> 4;
        const int c4  = slot & 15;
        const float4* ptr = xb + pos * F4_PER_POS + c4;
        float4 xg[8];
#pragma unroll
        for (int g = 0; g < 8; ++g) xg[g] = ptr[g * F4_PER_GROUP];
        int p = 0;
#pragma unroll
        for (int g = 0; g < 8; ++g) {
#pragma unroll
            for (int gp = g; gp < 8; ++gp, ++p) {
                acc[p] += xg[g].x * xg[gp].x + xg[g].y * xg[gp].y +
                          xg[g].z * xg[gp].z + xg[g].w * xg[gp].w;
            }
        }
    }

    // wave-level butterfly reduction (wave = 64 lanes)
#pragma unroll
    for (int p = 0; p < NPAIR; ++p) {
        float v = acc[p];
#pragma unroll
        for (int off = 32; off; off >>= 1) v += __shfl_xor(v, off, 64);
        acc[p] = v;
    }

    __shared__ float red[4][NPAIR];
    const int lane = tid & 63;
    const int wave = tid >> 6;
    if (lane == 0) {
#pragma unroll
        for (int p = 0; p < NPAIR; ++p) red[wave][p] = acc[p];
    }
    __syncthreads();
    if (tid < NPAIR) {
        P[blockIdx.x * NPAIR + tid] =
            red[0][tid] + red[1][tid] + red[2][tid] + red[3][tid];
    }
}

// ---------------------------------------------------------------------------
// Kernel 2: each block reduces its batch's 64 partial rows (9 KB, L2-hot),
// computes alpha2 in LDS, then writes its 1/64 share of the output.
// Output stores are nontemporal so the 16.8 MB write stream doesn't evict
// x from L2/L3 (pass-2 x re-read should be Infinity-Cache-served).
// grid = 1024, block = 256; 4 float4 outputs per thread.
// ---------------------------------------------------------------------------
__global__ __launch_bounds__(256) void out_kernel(
    const float* __restrict__ xf, const float* __restrict__ P,
    float* __restrict__ outf) {
    const float4* x = (const float4*)xf;
    float4* out = (float4*)outf;
    const int tid = threadIdx.x;
    const int b   = blockIdx.x >> 6;
    const int blk = blockIdx.x & 63;
    const float4* xb = x + (long)b * XB_F4;

    __shared__ float Sred[NPAIR][4];
    __shared__ float S36[NPAIR];
    __shared__ float alpha1s[8];
    __shared__ float alpha2s[8];

    if (tid < NPAIR * 4) {               // 144 threads: 4 lanes per pair
        const int p = tid >> 2;
        const int j = tid & 3;
        float v = 0.f;
#pragma unroll
        for (int k = 0; k < 16; ++k)
            v += P[(b * 64 + j * 16 + k) * NPAIR + p];
        Sred[p][j] = v;
    }
    __syncthreads();
    if (tid < NPAIR)
        S36[tid] = Sred[tid][0] + Sred[tid][1] + Sred[tid][2] + Sred[tid][3];
    __syncthreads();

    float row[8];
    float beta1 = 0.f;
    if (tid < 8) {
        const int g = tid;
#pragma unroll
        for (int gp = 0; gp < 8; ++gp) {
            const int a  = g < gp ? g : gp;
            const int bb = g < gp ? gp : g;
            row[gp] = S36[a * 8 - (a * (a - 1)) / 2 + (bb - a)];
            beta1 += row[gp];
        }
        beta1 *= 0.5f;                    // alpha0 = sigmoid(0) = 0.5
        alpha1s[tid] = 1.f / (1.f + expf(-beta1));
    }
    __syncthreads();
    if (tid < 8) {
        float beta2 = beta1;
#pragma unroll
        for (int gp = 0; gp < 8; ++gp) beta2 += alpha1s[gp] * row[gp];
        alpha2s[tid] = 1.f / (1.f + expf(-beta2));
    }
    __syncthreads();

    float a[8];
#pragma unroll
    for (int g = 0; g < 8; ++g) a[g] = alpha2s[g];

    const long obase = (long)b * SLOTS_PER_B;
#pragma unroll
    for (int i = 0; i < 4; ++i) {
        const int oslot = blk * 1024 + i * 256 + tid;   // [0, 65536)
        const int pos = oslot >> 4;
        const int c4  = oslot & 15;
        const float4* ptr = xb + pos * F4_PER_POS + c4;
        float4 r = make_float4(0.f, 0.f, 0.f, 0.f);
#pragma unroll
        for (int g = 0; g < 8; ++g) {
            const float4 v = ptr[g * F4_PER_GROUP];
            r.x += a[g] * v.x;
            r.y += a[g] * v.y;
            r.z += a[g] * v.z;
            r.w += a[g] * v.w;
        }
        f4v rv = {r.x, r.y, r.z, r.w};
        __builtin_nontemporal_store(rv, (f4v*)&out[obase + oslot]);
    }
}

extern "C" void kernel_launch(void* const* d_in, const int* in_sizes, int n_in,
                              void* d_out, int out_size, void* d_ws, size_t ws_size,
                              hipStream_t stream) {
    const float* x = (const float*)d_in[0];
    float* out = (float*)d_out;
    float* P = (float*)d_ws;             // 1024 * 36 floats = 147 KB partials

    gram_partial_kernel<<<NBLOCKS, 256, 0, stream>>>(x, P);
    out_kernel<<<NBLOCKS, 256, 0, stream>>>(x, P, out);
}